// Round 12
// baseline (76.055 us; speedup 1.0000x reference)
//
#include <hip/hip_runtime.h>
#include <hip/hip_bf16.h>

#define F      128
#define NROWS  2048
#define MROWS  2048
#define BN     128         // n-rows per pair block
#define BM     64          // m-cols per pair block
#define MT     (MROWS/BM)  // 32 m-tiles
#define NCH    16          // 16 chunks of 8 g
#define LOG2E  1.44269504088896340736f

// Per-wave private LDS strips (zero-barrier main loop):
//   row-chunk = 16 data floats (8 p0 | 8 p1) + 4 pad = 20 floats (80 B)
//   stride 80 ≡ 16 (mod 128): measured zero-conflict pattern (R10/R11)
// wave region per buffer: A strip 768 f (32 rows*20 + slop) | B strip 1280 f (64 rows*20)
#define ROWF   20
#define ABASE  0
#define BBASE  768
#define BUF_F  2048                      // floats per wave per buffer
#define WAVE_F (2 * BUF_F)               // 4096 floats per wave

typedef float f32x4 __attribute__((ext_vector_type(4)));

__device__ __forceinline__ void gload16(const float* g, float* l) {
    __builtin_amdgcn_global_load_lds(
        (const __attribute__((address_space(1))) void*)g,
        (__attribute__((address_space(3))) void*)l, 16, 0, 0);
}

// --- Kernel 1: projections + ELU/w2 precompute + w2sum ----------------------
// a = (embeds@W1)[n][g], b = (base@W1)[m][g], w = w2[g]
// Global layout: P[row][ch][0..7]=plane0(g=ch*8+o), [8..15]=plane1 (256 f/row)
// PA: p0=(a+1)*w, p1=exp(a)*w ; PB: p0=-b*w, p1=exp(-b)
// w*elu(a-b) + w = med3(p0A + p0B, p1A * p1B, w)   [median commutes with *w, any sign]
__global__ __launch_bounds__(256) void proj_kernel(
    const float* __restrict__ embeds, const float* __restrict__ base,
    const float* __restrict__ W1, const float* __restrict__ w2,
    float* __restrict__ PA, float* __restrict__ PB,
    float* __restrict__ w2sum)
{
    const int tid = threadIdx.x;
    const int sub = tid >> 7;
    const int g   = tid & 127;
    const int row = blockIdx.x * 2 + sub;

    __shared__ float xs[2][F];
    {
        const float* src = (row < NROWS) ? &embeds[(size_t)row * F]
                                         : &base[(size_t)(row - NROWS) * F];
        xs[sub][g] = src[g];
    }
    __syncthreads();

    float acc = 0.0f;
#pragma unroll 8
    for (int f = 0; f < F; ++f)
        acc = fmaf(xs[sub][f], W1[f * F + g], acc);

    const float wv = w2[g];
    const int   ch = g >> 3, o = g & 7;
    if (row < NROWS) {
        float* dst = PA + (size_t)row * 256 + ch * 16 + o;
        dst[0] = (acc + 1.0f) * wv;
        dst[8] = __builtin_amdgcn_exp2f(acc * LOG2E) * wv;
    } else {
        float* dst = PB + (size_t)(row - NROWS) * 256 + ch * 16 + o;
        dst[0] = -acc * wv;
        dst[8] = __builtin_amdgcn_exp2f(-acc * LOG2E);
    }

    if (blockIdx.x == 0 && tid < 64) {
        float s = w2[tid] + w2[tid + 64];
#pragma unroll
        for (int k = 1; k < 64; k <<= 1) s += __shfl_xor(s, k);
        if (tid == 0) *w2sum = s;
    }
}

// --- Kernel 2: pair kernel -----------------------------------------------------
// grid (16,32), 256 threads; tile 128(n)x64(m); tr=tid>>4, tc=tid&15; Rn=8,Rm=4.
// Wave w (tr in [4w,4w+4)) owns a PRIVATE LDS region: its 32 A-rows + all 64
// B-rows (duplicated per wave, L2-resident), double-buffered. Each wave stages
// its own region with 8 global_load_lds per chunk; per-wave vmcnt(0) replaces
// __syncthreads -> ZERO barriers in the main loop, waves drift freely.
__global__ __launch_bounds__(256, 2) void pair_kernel(
    const float* __restrict__ PA, const float* __restrict__ PB,
    const float* __restrict__ w2, const float* __restrict__ w2sum_p,
    const float* __restrict__ brew, float* __restrict__ partials)
{
    __shared__ float sbuf[4 * WAVE_F];   // 64 KB
    __shared__ float w2l[F];

    const int tid = threadIdx.x;
    const int w   = tid >> 6, l = tid & 63;
    const int nt  = blockIdx.x, mt = blockIdx.y;
    const int n0  = nt * BN,    m0 = mt * BM;
    const int tc  = tid & 15;
    const int trw = (tid >> 4) & 3;      // thread-row within wave
    const int wbase = w * WAVE_F;

    // --- staging source precompute: 8 gload instrs per chunk ---
    // t<3: A strip. lane slot = t*64+l; local row rl = slot/5 (pad slot %5==4
    // re-fetches slot 0). global A row = n0 + 4w + (rl&3) + 16*(rl>>2)
    // (rl>=32 slop reads stay inside ws and land in LDS slop -> never read).
    // t>=3: B strip. slot = (t-3)*64+l; global B row = m0 + slot/5.
    const float* ssrc[8];
#pragma unroll
    for (int t = 0; t < 8; ++t) {
        int slot, row;
        const float* basep;
        if (t < 3) {
            slot = t * 64 + l;
            const int rl = slot / 5;
            row = n0 + 4 * w + (rl & 3) + 16 * (rl >> 2);
            basep = PA;
        } else {
            slot = (t - 3) * 64 + l;
            row = m0 + slot / 5;
            basep = PB;
        }
        int rs = slot - (slot / 5) * 5;
        if (rs == 4) rs = 0;
        ssrc[t] = basep + (size_t)row * 256 + rs * 4;
    }

#define STAGE(CH, BUF) {                                                   \
    float* db = &sbuf[wbase + (BUF) * BUF_F];                              \
    gload16(ssrc[0] + (CH) * 16, db +    0);                               \
    gload16(ssrc[1] + (CH) * 16, db +  256);                               \
    gload16(ssrc[2] + (CH) * 16, db +  512);                               \
    gload16(ssrc[3] + (CH) * 16, db +  768);                               \
    gload16(ssrc[4] + (CH) * 16, db + 1024);                               \
    gload16(ssrc[5] + (CH) * 16, db + 1280);                               \
    gload16(ssrc[6] + (CH) * 16, db + 1536);                               \
    gload16(ssrc[7] + (CH) * 16, db + 1792); }

    float acc[8][4];
#pragma unroll
    for (int i = 0; i < 8; ++i)
#pragma unroll
        for (int j = 0; j < 4; ++j) acc[i][j] = 0.0f;

    STAGE(0, 0)
    if (tid < F) w2l[tid] = w2[tid];
    __syncthreads();                      // the ONLY barrier (w2l + initial stage)

#pragma unroll 1
    for (int ch = 0; ch < NCH; ++ch) {
        const int buf = ch & 1;
        if (ch + 1 < NCH) STAGE(ch + 1, buf ^ 1)

        const float* sa  = &sbuf[wbase + buf * BUF_F];
        const float* sbb = sa + BBASE;

#pragma unroll
        for (int h = 0; h < 2; ++h) {          // two 4-g halves of the 8-g chunk
            const float wq0 = w2l[ch * 8 + h * 4 + 0];
            const float wq1 = w2l[ch * 8 + h * 4 + 1];
            const float wq2 = w2l[ch * 8 + h * 4 + 2];
            const float wq3 = w2l[ch * 8 + h * 4 + 3];
            f32x4 b1v[4], bev[4];
#pragma unroll
            for (int j = 0; j < 4; ++j) {
                const float* bp = sbb + (tc + 16 * j) * ROWF + h * 4;
                b1v[j] = *(const f32x4*)bp;
                bev[j] = *(const f32x4*)(bp + 8);
            }
#pragma unroll
            for (int i = 0; i < 8; ++i) {
                const float* ap = sa + (i * 4 + trw) * ROWF + h * 4;
                const f32x4 a1 = *(const f32x4*)ap;
                const f32x4 ae = *(const f32x4*)(ap + 8);
#pragma unroll
                for (int j = 0; j < 4; ++j) {
                    const float s0 = __builtin_amdgcn_fmed3f(a1.x + b1v[j].x, ae.x * bev[j].x, wq0);
                    const float s1 = __builtin_amdgcn_fmed3f(a1.y + b1v[j].y, ae.y * bev[j].y, wq1);
                    const float s2 = __builtin_amdgcn_fmed3f(a1.z + b1v[j].z, ae.z * bev[j].z, wq2);
                    const float s3 = __builtin_amdgcn_fmed3f(a1.w + b1v[j].w, ae.w * bev[j].w, wq3);
                    acc[i][j] += (s0 + s1) + (s2 + s3);
                }
            }
        }
        // per-wave: ensure our next-buffer stage has landed before reading it
        asm volatile("s_waitcnt vmcnt(0)" ::: "memory");
    }
#undef STAGE

    const float w2sum = *w2sum_p;
    float rsv[4];
#pragma unroll
    for (int j = 0; j < 4; ++j) rsv[j] = brew[m0 + tc + 16 * j];

#pragma unroll
    for (int i = 0; i < 8; ++i) {
        float sw = 0.0f, swr = 0.0f;
#pragma unroll
        for (int j = 0; j < 4; ++j) {
            const float dist = fabsf(acc[i][j] - w2sum);
            const float wgt  = 1.0f / (dist + 1e-4f);
            sw += wgt;
            swr = fmaf(wgt, rsv[j], swr);
        }
#pragma unroll
        for (int k = 1; k < 16; k <<= 1) {   // reduce over tc (low 4 lane bits)
            sw  += __shfl_xor(sw, k);
            swr += __shfl_xor(swr, k);
        }
        if (tc == 0) {
            const int n = n0 + (4 * w + trw) + 16 * i;
            partials[((size_t)n * MT + mt) * 2 + 0] = sw;
            partials[((size_t)n * MT + mt) * 2 + 1] = swr;
        }
    }
}

// --- Kernel 3: reduce tile partials, divide ------------------------------------
__global__ __launch_bounds__(256) void finalize_kernel(
    const float* __restrict__ partials, float* __restrict__ out)
{
    const int n = blockIdx.x * 256 + threadIdx.x;
    if (n < NROWS) {
        float sw = 0.0f, swr = 0.0f;
#pragma unroll
        for (int t = 0; t < MT; ++t) {
            sw  += partials[((size_t)n * MT + t) * 2 + 0];
            swr += partials[((size_t)n * MT + t) * 2 + 1];
        }
        out[n] = swr / sw;
    }
}

extern "C" void kernel_launch(void* const* d_in, const int* in_sizes, int n_in,
                              void* d_out, int out_size, void* d_ws, size_t ws_size,
                              hipStream_t stream)
{
    const float* embeds       = (const float*)d_in[0];  // [2048,128]
    const float* base_embeds  = (const float*)d_in[1];  // [2048,128]
    const float* base_rewards = (const float*)d_in[2];  // [2048]
    const float* W1           = (const float*)d_in[3];  // [128,128] (in,out)
    const float* w2           = (const float*)d_in[4];  // [128,1]
    float* out = (float*)d_out;

    // ws: partials [2048*MT*2] | PA [2048*256] | PB [2048*256] | w2sum[1]
    float* partials = (float*)d_ws;
    float* PA  = partials + (size_t)NROWS * MT * 2;
    float* PB  = PA + (size_t)NROWS * 256;
    float* w2s = PB + (size_t)MROWS * 256;

    proj_kernel<<<(NROWS + MROWS) / 2, 256, 0, stream>>>(
        embeds, base_embeds, W1, w2, PA, PB, w2s);

    dim3 grid2(NROWS / BN, MROWS / BM);
    pair_kernel<<<grid2, 256, 0, stream>>>(PA, PB, w2, w2s, base_rewards, partials);

    finalize_kernel<<<(NROWS + 255) / 256, 256, 0, stream>>>(partials, out);
}